// Round 11
// baseline (1075.857 us; speedup 1.0000x reference)
//
#include <hip/hip_runtime.h>
#include <hip/hip_bf16.h>

#define E_NUM 64
#define IN_SZ 512
#define OUT_SZ 512
#define N_TOK 131072
#define CAP 3072

#define BM 128
#define BN 256
#define BK 32
#define THREADS 256
#define RT_MAX 24   // CAP/BM
#define CT_NUM 2    // OUT/BN
#define JT 16       // IN_SZ/BK
#define NWG (E_NUM * RT_MAX * CT_NUM)

typedef __attribute__((ext_vector_type(8))) short short8;
typedef __attribute__((ext_vector_type(4))) float f32x4;

__device__ inline unsigned short f2bf(float f) {
    unsigned int u = __float_as_uint(f);
    unsigned int r = (u + 0x7FFF + ((u >> 16) & 1)) >> 16;
    return (unsigned short)r;
}

#define GLOAD_LDS16(g, l)                                                     \
    __builtin_amdgcn_global_load_lds(                                         \
        (const __attribute__((address_space(1))) void*)(g),                   \
        (__attribute__((address_space(3))) void*)(l), 16, 0, 0)

// ---------------- kernel 1: exclusive prefix sum of expert sizes ----------
__global__ void offsets_kernel(const int* __restrict__ sizes, int* __restrict__ offs) {
    int e = threadIdx.x;
    int s = 0;
    for (int i = 0; i < e; ++i) s += sizes[i];
    offs[e] = s;
}

// ---------------- kernel 2: W [E][K][N] f32 -> WT [E][N][K] bf16 ----------
__global__ __launch_bounds__(256) void prep_wt(const float* __restrict__ W,
                                               unsigned short* __restrict__ WT) {
    __shared__ float t[32][33];
    int k0 = blockIdx.x * 32, n0 = blockIdx.y * 32, e = blockIdx.z;
    const float* We = W + (size_t)e * IN_SZ * OUT_SZ;
    int tid = threadIdx.x;
    int r = tid >> 3, c4 = (tid & 7) * 4;
    float4 v = *(const float4*)(We + (size_t)(k0 + r) * OUT_SZ + n0 + c4);
    t[r][c4 + 0] = v.x; t[r][c4 + 1] = v.y; t[r][c4 + 2] = v.z; t[r][c4 + 3] = v.w;
    __syncthreads();
    ushort4 o;
    o.x = f2bf(t[c4 + 0][r]);
    o.y = f2bf(t[c4 + 1][r]);
    o.z = f2bf(t[c4 + 2][r]);
    o.w = f2bf(t[c4 + 3][r]);
    unsigned short* O = WT + (size_t)e * IN_SZ * OUT_SZ + (size_t)(n0 + r) * IN_SZ + k0 + c4;
    *(ushort4*)O = o;
}

// ---------------- kernel 3: 40KB-LDS max-TLP grouped GEMM -----------------
// R1-R10 model: all well-occupied configs deliver 7-8 TB/s to CUs; winner =
// min delivered bytes (128x256 tile, 1.35 GB) AND >=4 blocks/CU.
//   LDS 40 KB: A SINGLE-buffered (8 KB) + B double-buffered (2x16 KB)
//     -> 4 blocks/CU at 256 thr (16 waves/CU).
//   VGPR <= 128: only A-frag reads precede the anti-overwrite barrier
//     (B is dbuf -> B-frag reads after it, interleaved with MFMA);
//     live-across-barrier = acc 64 + af 16 + ar 16 + addr ~14.
//   Plain __syncthreads (no asm fences - R10: pinning hurts at high TLP).
// Swizzle (verified 0-conflict): 16B-slot ^= (row>>1)&3 within 64B k-row;
// B pre-swizzled at global source (involution, rule #21).
__global__ __launch_bounds__(THREADS, 4) void gemm_moe(
    const float* __restrict__ A, const int* __restrict__ sizes,
    const unsigned short* __restrict__ WT, const int* __restrict__ offs,
    float* __restrict__ out)
{
    // bijective XCD swizzle: 3072 blocks, 384 per XCD chunk
    int b0 = blockIdx.x;
    int wg = (b0 & 7) * (NWG / 8) + (b0 >> 3);
    int ct = wg & (CT_NUM - 1);
    int rt = (wg >> 1) % RT_MAX;
    int e  = wg / (RT_MAX * CT_NUM);

    int size_e = sizes[e];
    int rows0 = rt * BM;
    if (rows0 >= size_e) return;
    int off_e = offs[e];
    int rows_rem = size_e - rows0;                      // >= 1
    int maxr = (rows_rem < BM ? rows_rem : BM) - 1;

    __shared__ unsigned short lsA[BM * BK];      // 8 KB  (single buffer)
    __shared__ unsigned short lsB[2][BN * BK];   // 2 x 16 KB -> 40 KB total

    int tid = threadIdx.x, l = tid & 63, w = tid >> 6;
    const char* WTe = (const char*)(WT + (size_t)e * IN_SZ * OUT_SZ);
    const float* Abase = A + (size_t)(off_e + rows0) * IN_SZ;

    // ---- A staging geometry (idx = tid + 256*i, i<4; row=idx>>3) ----
    const float* ap[4];
    int aw[4];
    #pragma unroll
    for (int i = 0; i < 4; ++i) {
        int idx = tid + THREADS * i;
        int row = idx >> 3, c4 = idx & 7;
        int gr = row <= maxr ? row : maxr;
        ap[i] = Abase + (size_t)gr * IN_SZ + c4 * 4;
        aw[i] = row * 64 + ((c4 * 8) ^ (((row >> 1) & 3) << 4));
    }
    // ---- B staging geometry (chunks c = w*4+i, c<16; LDS row c*16+l>>2) --
    const char* gB[4];
    #pragma unroll
    for (int i = 0; i < 4; ++i) {
        int c = w * 4 + i;
        int n = c * 16 + (l >> 2);
        int csrc = ((l & 3) * 16) ^ (((l >> 3) & 3) << 4);
        gB[i] = WTe + (size_t)(ct * BN + n) * (IN_SZ * 2) + csrc;
    }

    float4 ar[2][4];   // 2 A register sets (load j+2 while j+1 awaits write)

    auto loadA = [&](int kt, int p) {
        #pragma unroll
        for (int i = 0; i < 4; ++i)
            ar[p][i] = *(const float4*)(ap[i] + kt * BK);
    };
    auto writeA = [&](int p) {
        #pragma unroll
        for (int i = 0; i < 4; ++i) {
            ushort4 pk;
            pk.x = f2bf(ar[p][i].x); pk.y = f2bf(ar[p][i].y);
            pk.z = f2bf(ar[p][i].z); pk.w = f2bf(ar[p][i].w);
            *(ushort4*)((char*)&lsA[0] + aw[i]) = pk;
        }
    };
    auto stageB = [&](int buf, int kt) {
        #pragma unroll
        for (int i = 0; i < 4; ++i)
            GLOAD_LDS16(gB[i] + kt * 64, &lsB[buf][(w * 4 + i) * 512]);
    };

    int wm = (w >> 1) * 64, wn = (w & 1) * 128;
    int lrow = l & 15;
    int cb = ((l >> 4) * 16) ^ (((l >> 1) & 3) << 4);

    f32x4 acc[4][8] = {};

    // ---- prologue: A0,A1 -> regs; A0 -> LDS; B0 -> LDS ----
    loadA(0, 0); stageB(0, 0);
    loadA(1, 1);
    writeA(0);                 // compiler waits A0 loads only
    __syncthreads();           // A0 + B0 visible

    #pragma unroll
    for (int j = 0; j < JT; ++j) {
        // A-frag reads of tile j (must precede the overwrite barrier)
        short8 af[4];
        const char* pA = (const char*)&lsA[0];
        #pragma unroll
        for (int m = 0; m < 4; ++m)
            af[m] = *(const short8*)(pA + (wm + m * 16 + lrow) * 64 + cb);
        __syncthreads();       // all waves consumed A(j); lsA free

        if (j + 1 < JT) {
            writeA((j + 1) & 1);              // cvt + ds_write A(j+1)
            stageB((j + 1) & 1, j + 1);       // DMA B(j+1) -> other buf
        }
        if (j + 2 < JT) loadA(j + 2, (j + 2) & 1);  // refill freed reg set

        // B-frag reads of tile j (dbuf - safe after barrier) + MFMA
        const char* pB = (const char*)&lsB[j & 1][0];
        __builtin_amdgcn_s_setprio(1);
        #pragma unroll
        for (int n = 0; n < 8; ++n) {
            short8 bf = *(const short8*)(pB + (wn + n * 16 + lrow) * 64 + cb);
            #pragma unroll
            for (int m = 0; m < 4; ++m)
                acc[m][n] = __builtin_amdgcn_mfma_f32_16x16x32_bf16(
                    af[m], bf, acc[m][n], 0, 0, 0);
        }
        __builtin_amdgcn_s_setprio(0);
        __syncthreads();       // A(j+1) writes + B(j+1) DMA landed
    }

    // epilogue: C/D layout col = lane&15, row = (lane>>4)*4 + reg
    float* outb = out + (size_t)(off_e + rows0) * OUT_SZ + ct * BN + wn;
    #pragma unroll
    for (int m = 0; m < 4; ++m) {
        #pragma unroll
        for (int j = 0; j < 4; ++j) {
            int rl = wm + m * 16 + (l >> 4) * 4 + j;
            if (rl < rows_rem) {
                float* po = outb + (size_t)rl * OUT_SZ + lrow;
                #pragma unroll
                for (int n = 0; n < 8; ++n)
                    po[n * 16] = acc[m][n][j];
            }
        }
    }
}

extern "C" void kernel_launch(void* const* d_in, const int* in_sizes, int n_in,
                              void* d_out, int out_size, void* d_ws, size_t ws_size,
                              hipStream_t stream) {
    const float* A      = (const float*)d_in[0];
    const int* sizes    = (const int*)d_in[1];
    const float* W      = (const float*)d_in[2];
    float* out          = (float*)d_out;

    unsigned short* WT  = (unsigned short*)d_ws;                       // 32 MB
    int* offs           = (int*)((char*)d_ws + (size_t)E_NUM * IN_SZ * OUT_SZ * 2);

    offsets_kernel<<<1, E_NUM, 0, stream>>>(sizes, offs);
    prep_wt<<<dim3(IN_SZ / 32, OUT_SZ / 32, E_NUM), 256, 0, stream>>>(W, WT);
    gemm_moe<<<NWG, THREADS, 0, stream>>>(A, sizes, WT, offs, out);
}

// Round 12
// 209.977 us; speedup vs baseline: 5.1237x; 5.1237x over previous
//
#include <hip/hip_runtime.h>
#include <hip/hip_bf16.h>

#define E_NUM 64
#define IN_SZ 512
#define OUT_SZ 512
#define N_TOK 131072
#define CAP 3072

#define BM 128
#define BN 256
#define BK 32
#define THREADS 512
#define RT_MAX 24   // CAP/BM
#define CT_NUM 2    // OUT/BN
#define JT 16       // IN_SZ/BK
#define NWG (E_NUM * RT_MAX * CT_NUM)

typedef __attribute__((ext_vector_type(8))) short short8;
typedef __attribute__((ext_vector_type(4))) float f32x4;

__device__ inline unsigned short f2bf(float f) {
    unsigned int u = __float_as_uint(f);
    unsigned int r = (u + 0x7FFF + ((u >> 16) & 1)) >> 16;
    return (unsigned short)r;
}

#define GLOAD_LDS16(g, l)                                                     \
    __builtin_amdgcn_global_load_lds(                                         \
        (const __attribute__((address_space(1))) void*)(g),                   \
        (__attribute__((address_space(3))) void*)(l), 16, 0, 0)

// ---------------- kernel 1: exclusive prefix sum of expert sizes ----------
__global__ void offsets_kernel(const int* __restrict__ sizes, int* __restrict__ offs) {
    int e = threadIdx.x;
    int s = 0;
    for (int i = 0; i < e; ++i) s += sizes[i];
    offs[e] = s;
}

// ---------------- kernel 2: W [E][K][N] f32 -> WT [E][N][K] bf16 ----------
__global__ __launch_bounds__(256) void prep_wt(const float* __restrict__ W,
                                               unsigned short* __restrict__ WT) {
    __shared__ float t[32][33];
    int k0 = blockIdx.x * 32, n0 = blockIdx.y * 32, e = blockIdx.z;
    const float* We = W + (size_t)e * IN_SZ * OUT_SZ;
    int tid = threadIdx.x;
    int r = tid >> 3, c4 = (tid & 7) * 4;
    float4 v = *(const float4*)(We + (size_t)(k0 + r) * OUT_SZ + n0 + c4);
    t[r][c4 + 0] = v.x; t[r][c4 + 1] = v.y; t[r][c4 + 2] = v.z; t[r][c4 + 3] = v.w;
    __syncthreads();
    ushort4 o;
    o.x = f2bf(t[c4 + 0][r]);
    o.y = f2bf(t[c4 + 1][r]);
    o.z = f2bf(t[c4 + 2][r]);
    o.w = f2bf(t[c4 + 3][r]);
    unsigned short* O = WT + (size_t)e * IN_SZ * OUT_SZ + (size_t)(n0 + r) * IN_SZ + k0 + c4;
    *(ushort4*)O = o;
}

// ---------------- kernel 3: 16-waves/CU min-bytes grouped GEMM ------------
// The R1-R11 ledger: delivery rate tracks waves/CU; min-bytes tile is
// 128x256 (1.35 GB). The never-tested cell = BOTH. Register law (R10/R11):
// unified VGPR+AGPR file -> 4 waves/EU needs TOTAL <= 128 -> wave tile must
// be 64x64 (acc[4][4]=64). So: 512 thr / 8 waves (2x4 grid of 64x64),
// LDS 48 KB (A 2x8K bf16 + B 2x16K) -> 2 blocks/CU -> 16 waves/CU.
// R1-vs-R10 lesson (m141): NO asm fences/pins at high TLP -> plain
// __syncthreads, one per iteration.
// Swizzle (verified 0-conflict): 16B-slot ^= (row>>1)&3 within 64B k-row;
// B pre-swizzled at global source (involution, rule #21).
__global__ __launch_bounds__(THREADS, 4) void gemm_moe(
    const float* __restrict__ A, const int* __restrict__ sizes,
    const unsigned short* __restrict__ WT, const int* __restrict__ offs,
    float* __restrict__ out)
{
    // bijective XCD swizzle: 3072 blocks, 384 per XCD chunk
    int b0 = blockIdx.x;
    int wg = (b0 & 7) * (NWG / 8) + (b0 >> 3);
    int ct = wg & (CT_NUM - 1);
    int rt = (wg >> 1) % RT_MAX;
    int e  = wg / (RT_MAX * CT_NUM);

    int size_e = sizes[e];
    int rows0 = rt * BM;
    if (rows0 >= size_e) return;
    int off_e = offs[e];
    int rows_rem = size_e - rows0;                      // >= 1
    int maxr = (rows_rem < BM ? rows_rem : BM) - 1;

    __shared__ unsigned short lsA[2][BM * BK];   // 2 x 8 KB
    __shared__ unsigned short lsB[2][BN * BK];   // 2 x 16 KB -> 48 KB total

    int tid = threadIdx.x, l = tid & 63, w = tid >> 6;   // w in 0..7
    const char* WTe = (const char*)(WT + (size_t)e * IN_SZ * OUT_SZ);
    const float* Abase = A + (size_t)(off_e + rows0) * IN_SZ;

    // ---- A staging geometry (idx = tid + 512*i, i<2; row = idx>>3) ----
    const float* ap[2];
    int aw[2];
    #pragma unroll
    for (int i = 0; i < 2; ++i) {
        int idx = tid + THREADS * i;        // 0..1023 float4 units
        int row = idx >> 3, c4 = idx & 7;   // row 0..127
        int gr = row <= maxr ? row : maxr;
        ap[i] = Abase + (size_t)gr * IN_SZ + c4 * 4;
        aw[i] = row * 64 + ((c4 * 8) ^ (((row >> 1) & 3) << 4));
    }
    // ---- B staging geometry (chunks c = w*2+i, c<16; LDS row c*16+l>>2) --
    const char* gB[2];
    #pragma unroll
    for (int i = 0; i < 2; ++i) {
        int c = w * 2 + i;
        int n = c * 16 + (l >> 2);
        int csrc = ((l & 3) * 16) ^ (((l >> 3) & 3) << 4);
        gB[i] = WTe + (size_t)(ct * BN + n) * (IN_SZ * 2) + csrc;
    }

    float4 ar[2];      // single in-flight A register set (8 VGPRs)

    auto loadA = [&](int kt) {
        #pragma unroll
        for (int i = 0; i < 2; ++i)
            ar[i] = *(const float4*)(ap[i] + kt * BK);
    };
    auto writeA = [&](int buf) {
        #pragma unroll
        for (int i = 0; i < 2; ++i) {
            ushort4 pk;
            pk.x = f2bf(ar[i].x); pk.y = f2bf(ar[i].y);
            pk.z = f2bf(ar[i].z); pk.w = f2bf(ar[i].w);
            *(ushort4*)((char*)&lsA[buf][0] + aw[i]) = pk;
        }
    };
    auto stageB = [&](int buf, int kt) {
        #pragma unroll
        for (int i = 0; i < 2; ++i)
            GLOAD_LDS16(gB[i] + kt * 64, &lsB[buf][(w * 2 + i) * 512]);
    };

    int wm = (w >> 2) * 64, wn = (w & 3) * 64;   // 2x4 grid of 64x64
    int lrow = l & 15;
    int cb = ((l >> 4) * 16) ^ (((l >> 1) & 3) << 4);

    f32x4 acc[4][4] = {};

    // ---- prologue: tile 0 staged ----
    loadA(0); stageB(0, 0);
    writeA(0);                 // compiler waits A0 loads only
    __syncthreads();           // drains B0 DMA + A0 ds_writes

    // ---- main loop: one barrier per iteration, no asm pins ----
    #pragma unroll
    for (int j = 0; j < JT; ++j) {
        int cur = j & 1;
        if (j + 1 < JT) {
            loadA(j + 1);            // global->regs, consumed after MFMA
            stageB(cur ^ 1, j + 1);  // global->LDS DMA into other buffer
        }
        // fragments of tile j + MFMA
        {
            const char* pA = (const char*)&lsA[cur][0];
            const char* pB = (const char*)&lsB[cur][0];
            short8 af[4];
            #pragma unroll
            for (int m = 0; m < 4; ++m)
                af[m] = *(const short8*)(pA + (wm + m * 16 + lrow) * 64 + cb);
            __builtin_amdgcn_s_setprio(1);
            #pragma unroll
            for (int n = 0; n < 4; ++n) {
                short8 bf = *(const short8*)(pB + (wn + n * 16 + lrow) * 64 + cb);
                #pragma unroll
                for (int m = 0; m < 4; ++m)
                    acc[m][n] = __builtin_amdgcn_mfma_f32_16x16x32_bf16(
                        af[m], bf, acc[m][n], 0, 0, 0);
            }
            __builtin_amdgcn_s_setprio(0);
        }
        if (j + 1 < JT)
            writeA(cur ^ 1);         // cvt+ds_write; A loads had MFMA-long slack
        if (j < JT - 1)
            __syncthreads();         // drains DMA + ds_writes, one barrier/iter
    }

    // epilogue: C/D layout col = lane&15, row = (lane>>4)*4 + reg
    float* outb = out + (size_t)(off_e + rows0) * OUT_SZ + ct * BN + wn;
    #pragma unroll
    for (int m = 0; m < 4; ++m) {
        #pragma unroll
        for (int j = 0; j < 4; ++j) {
            int rl = wm + m * 16 + (l >> 4) * 4 + j;
            if (rl < rows_rem) {
                float* po = outb + (size_t)rl * OUT_SZ + lrow;
                #pragma unroll
                for (int n = 0; n < 4; ++n)
                    po[n * 16] = acc[m][n][j];
            }
        }
    }
}

extern "C" void kernel_launch(void* const* d_in, const int* in_sizes, int n_in,
                              void* d_out, int out_size, void* d_ws, size_t ws_size,
                              hipStream_t stream) {
    const float* A      = (const float*)d_in[0];
    const int* sizes    = (const int*)d_in[1];
    const float* W      = (const float*)d_in[2];
    float* out          = (float*)d_out;

    unsigned short* WT  = (unsigned short*)d_ws;                       // 32 MB
    int* offs           = (int*)((char*)d_ws + (size_t)E_NUM * IN_SZ * OUT_SZ * 2);

    offsets_kernel<<<1, E_NUM, 0, stream>>>(sizes, offs);
    prep_wt<<<dim3(IN_SZ / 32, OUT_SZ / 32, E_NUM), 256, 0, stream>>>(W, WT);
    gemm_moe<<<NWG, THREADS, 0, stream>>>(A, sizes, WT, offs, out);
}